// Round 11
// baseline (1663.394 us; speedup 1.0000x reference)
//
#include <hip/hip_runtime.h>
#include <hip/hip_bf16.h>

#define Bc 32
#define NPGc 290
#define Nn 9280
#define Ec 74240
#define LPc 900
#define INFc 75
#define Dd 128
#define HKc 768
#define LQ 885
#define LQP 896        // LQ padded to /16 (tail zeroed in qT)
#define S1 904
#define S2 896
#define S3 888
#define NT 78          // upper-triangle 64x64 tiles of 768x768
#define TSZ 4096       // 64*64

typedef __attribute__((ext_vector_type(8))) short bf16x8;
typedef __attribute__((ext_vector_type(16))) float f32x16;

static __device__ __forceinline__ unsigned short f2bf(float v){
  unsigned int u = __float_as_uint(v);
  unsigned int r = u + 0x7FFFu + ((u >> 16) & 1u);
  return (unsigned short)(r >> 16);
}
static __device__ __forceinline__ float bf2f(unsigned short b){
  return __uint_as_float(((unsigned int)b) << 16);
}

__global__ void k_sentinel(float* out, float val){
  int t = threadIdx.x;
  if (t < 128) out[t] = val;
}

// ---------------- GCN ----------------
__global__ void k_h0(float* __restrict__ h0, const float* __restrict__ nh, const float* __restrict__ Wi){
  int n = blockIdx.x, j = threadIdx.x;
  __shared__ float arow[INFc];
  if (j < INFc) arow[j] = nh[(size_t)n*INFc + j];
  __syncthreads();
  float s = 0.f;
  #pragma unroll 5
  for (int k=0;k<INFc;k++) s += arow[k]*Wi[(size_t)k*Dd + j];
  h0[(size_t)n*Dd + j] = s;
}

__global__ void k_build_adj(float* __restrict__ A, const int* __restrict__ src, const int* __restrict__ dst){
  int e = blockIdx.x*blockDim.x + threadIdx.x;
  if (e >= Ec) return;
  int s = src[e], d = dst[e];
  int b = d / NPGc;
  int dl = d - b*NPGc, sl = s - b*NPGc;
  atomicAdd(&A[((size_t)b*NPGc + dl)*NPGc + sl], 1.f);
}

// pre-transpose+split GCN weights into fragment-ready layout:
// dst[gl][chunk c][j'][16 kslot], hi at [0,NW), lo at [NW,2NW)
__global__ void k_wsplit(unsigned short* __restrict__ dstW, unsigned short* __restrict__ dstWr,
                         const float* __restrict__ W, const float* __restrict__ Wr){
  int idx = blockIdx.x*256 + threadIdx.x;   // over 9*128*128
  if (idx >= 9*Dd*Dd) return;
  int gl = idx >> 14;
  int r  = idx & 16383;
  int k  = r >> 7, j = r & 127;
  int c = k >> 4, slot = k & 15;
  size_t o = ((((size_t)gl*8 + c)*Dd + j) << 4) + slot;
  const size_t NW = (size_t)9*8*Dd*16;
  float v = W[idx];
  unsigned short hi = f2bf(v);
  dstW[o] = hi; dstW[NW + o] = f2bf(v - bf2f(hi));
  float u = Wr[idx];
  unsigned short hr = f2bf(u);
  dstWr[o] = hr; dstWr[NW + o] = f2bf(u - bf2f(hr));
}

// agg = A @ h via MFMA. A exact in bf16 (integer counts). h split hi/lo at stage.
__global__ void k_aggm(unsigned short* __restrict__ aggH, unsigned short* __restrict__ aggL,
                       const float* __restrict__ inb, size_t istride,
                       const float* __restrict__ Adj){
  int g = blockIdx.z, b = blockIdx.y;
  int i0 = blockIdx.x*64;
  const float* h = inb + (size_t)g*istride + (size_t)b*NPGc*Dd;
  const float* Ab = Adj + (size_t)b*NPGc*NPGc;
  __shared__ unsigned short Bh[128*24], Bl[128*24];
  int tid = threadIdx.x;
  int w = tid>>6, l = tid&63, lr = l&31, lg = l>>5;
  int mh = w>>1, nh = w&1;
  int kr = tid>>4, jq = tid&15;
  f32x16 acc0={}, acc1={};
  for (int c=0;c<19;c++){
    int k0 = c*16;
    {
      int ci = k0 + kr;
      if (ci < NPGc){
        const float* hr_ = h + (size_t)ci*Dd + jq*8;
        #pragma unroll
        for (int m=0;m<8;m++){
          float v = hr_[m];
          unsigned short hi16 = f2bf(v);
          Bh[(jq*8+m)*24 + kr] = hi16;
          Bl[(jq*8+m)*24 + kr] = f2bf(v - bf2f(hi16));
        }
      } else {
        #pragma unroll
        for (int m=0;m<8;m++){ Bh[(jq*8+m)*24+kr]=0; Bl[(jq*8+m)*24+kr]=0; }
      }
    }
    __syncthreads();
    int row = i0 + mh*32 + lr;
    bf16x8 aA = {0,0,0,0,0,0,0,0};
    if (row < NPGc && k0+15 < NPGc){
      const float* ar_ = Ab + (size_t)row*NPGc + k0 + lg*8;
      #pragma unroll
      for (int m=0;m<8;m++) aA[m] = (short)f2bf(ar_[m]);
    } else if (row < NPGc){
      #pragma unroll
      for (int m=0;m<8;m++){
        int k = k0 + lg*8 + m;
        aA[m] = (short)((k < NPGc) ? f2bf(Ab[(size_t)row*NPGc + k]) : 0);
      }
    }
    bf16x8 b0H = *(const bf16x8*)&Bh[(nh*64+lr)*24 + lg*8];
    bf16x8 b0L = *(const bf16x8*)&Bl[(nh*64+lr)*24 + lg*8];
    bf16x8 b1H = *(const bf16x8*)&Bh[(nh*64+32+lr)*24 + lg*8];
    bf16x8 b1L = *(const bf16x8*)&Bl[(nh*64+32+lr)*24 + lg*8];
    acc0 = __builtin_amdgcn_mfma_f32_32x32x16_bf16(aA, b0H, acc0, 0, 0, 0);
    acc0 = __builtin_amdgcn_mfma_f32_32x32x16_bf16(aA, b0L, acc0, 0, 0, 0);
    acc1 = __builtin_amdgcn_mfma_f32_32x32x16_bf16(aA, b1H, acc1, 0, 0, 0);
    acc1 = __builtin_amdgcn_mfma_f32_32x32x16_bf16(aA, b1L, acc1, 0, 0, 0);
    __syncthreads();
  }
  size_t gb = ((size_t)g*Bc + b)*NPGc;
  int j0 = nh*64 + lr;
  #pragma unroll
  for (int reg=0; reg<16; reg++){
    int rowl = (reg&3) + 8*(reg>>2) + 4*lg;
    int i = i0 + mh*32 + rowl;
    if (i < NPGc){
      size_t base = (gb + i)*Dd;
      float v0 = acc0[reg];
      unsigned short h0_ = f2bf(v0);
      aggH[base + j0] = h0_;
      aggL[base + j0] = f2bf(v0 - bf2f(h0_));
      float v1 = acc1[reg];
      unsigned short h1_ = f2bf(v1);
      aggH[base + j0 + 32] = h1_;
      aggL[base + j0 + 32] = f2bf(v1 - bf2f(h1_));
    }
  }
}

// out = relu(agg@W + b) + relu(h@Wr + br). No LDS/barriers.
__global__ void k_gcnlin(float* __restrict__ outb, size_t ostride,
                         const unsigned short* __restrict__ aggH, const unsigned short* __restrict__ aggL,
                         const float* __restrict__ inb, size_t istride,
                         const unsigned short* __restrict__ WTs, const unsigned short* __restrict__ WrTs,
                         const float* __restrict__ ball, const float* __restrict__ brall, int lno){
  int g = blockIdx.y;
  int m0 = blockIdx.x*64;
  int gl = g*3 + lno;
  const size_t NW = (size_t)9*8*Dd*16;
  int tid = threadIdx.x;
  int w=tid>>6, l=tid&63, lr=l&31, lg=l>>5;
  int mh=w>>1, nh=w&1;
  const float* hin = inb + (size_t)g*istride;
  const unsigned short* agH = aggH + (size_t)g*Nn*Dd;
  const unsigned short* agL = aggL + (size_t)g*Nn*Dd;
  f32x16 aw0={},aw1={},ar0={},ar1={};
  int row = m0 + mh*32 + lr;
  for (int c=0;c<8;c++){
    int k0 = c*16;
    bf16x8 gH = *(const bf16x8*)&agH[(size_t)row*Dd + k0 + lg*8];
    bf16x8 gL = *(const bf16x8*)&agL[(size_t)row*Dd + k0 + lg*8];
    bf16x8 hH, hL;
    {
      const float* hp = hin + (size_t)row*Dd + k0 + lg*8;
      #pragma unroll
      for (int m=0;m<8;m++){
        float v = hp[m];
        unsigned short x = f2bf(v);
        hH[m] = (short)x;
        hL[m] = (short)f2bf(v - bf2f(x));
      }
    }
    size_t wb0 = ((((size_t)gl*8 + c)*Dd) + nh*64 + lr)*16 + (size_t)lg*8;
    size_t wb1 = wb0 + 32*16;
    bf16x8 w0H = *(const bf16x8*)&WTs[wb0];
    bf16x8 w0L = *(const bf16x8*)&WTs[NW + wb0];
    bf16x8 w1H = *(const bf16x8*)&WTs[wb1];
    bf16x8 w1L = *(const bf16x8*)&WTs[NW + wb1];
    bf16x8 r0H = *(const bf16x8*)&WrTs[wb0];
    bf16x8 r0L = *(const bf16x8*)&WrTs[NW + wb0];
    bf16x8 r1H = *(const bf16x8*)&WrTs[wb1];
    bf16x8 r1L = *(const bf16x8*)&WrTs[NW + wb1];
    aw0 = __builtin_amdgcn_mfma_f32_32x32x16_bf16(gH, w0H, aw0, 0,0,0);
    aw0 = __builtin_amdgcn_mfma_f32_32x32x16_bf16(gH, w0L, aw0, 0,0,0);
    aw0 = __builtin_amdgcn_mfma_f32_32x32x16_bf16(gL, w0H, aw0, 0,0,0);
    aw1 = __builtin_amdgcn_mfma_f32_32x32x16_bf16(gH, w1H, aw1, 0,0,0);
    aw1 = __builtin_amdgcn_mfma_f32_32x32x16_bf16(gH, w1L, aw1, 0,0,0);
    aw1 = __builtin_amdgcn_mfma_f32_32x32x16_bf16(gL, w1H, aw1, 0,0,0);
    ar0 = __builtin_amdgcn_mfma_f32_32x32x16_bf16(hH, r0H, ar0, 0,0,0);
    ar0 = __builtin_amdgcn_mfma_f32_32x32x16_bf16(hH, r0L, ar0, 0,0,0);
    ar0 = __builtin_amdgcn_mfma_f32_32x32x16_bf16(hL, r0H, ar0, 0,0,0);
    ar1 = __builtin_amdgcn_mfma_f32_32x32x16_bf16(hH, r1H, ar1, 0,0,0);
    ar1 = __builtin_amdgcn_mfma_f32_32x32x16_bf16(hH, r1L, ar1, 0,0,0);
    ar1 = __builtin_amdgcn_mfma_f32_32x32x16_bf16(hL, r1H, ar1, 0,0,0);
  }
  float* out = outb + (size_t)g*ostride;
  int j0 = nh*64 + lr;
  float b0 = ball[gl*Dd + j0], b1 = ball[gl*Dd + j0 + 32];
  float c0 = brall[gl*Dd + j0], c1 = brall[gl*Dd + j0 + 32];
  #pragma unroll
  for (int reg=0; reg<16; reg++){
    int rowl = (reg&3)+8*(reg>>2)+4*lg;
    int i = m0 + mh*32 + rowl;
    out[(size_t)i*Dd + j0]      = fmaxf(aw0[reg]+b0,0.f) + fmaxf(ar0[reg]+c0,0.f);
    out[(size_t)i*Dd + j0 + 32] = fmaxf(aw1[reg]+b1,0.f) + fmaxf(ar1[reg]+c1,0.f);
  }
}

// ---------------- ProteinCNN ----------------
__global__ void k_embed(float* __restrict__ x, const int* __restrict__ vp, const float* __restrict__ emb){
  int t = blockIdx.x*blockDim.x + threadIdx.x;
  int d = blockIdx.y, b = blockIdx.z;
  if (t >= LPc) return;
  int tok = vp[b*LPc + t];
  x[((size_t)b*Dd + d)*LPc + t] = emb[(size_t)tok*Dd + d];
}

// pack conv weights (BN scale folded in) fragment-ready: hi[(c*128+o)*16+s], lo at +C*2048
__global__ void k_wpack16(unsigned short* __restrict__ wp, const float* __restrict__ w,
                          const float* __restrict__ scale, int KW, int C){
  int idx = blockIdx.x*256 + threadIdx.x;
  int tot = C*2048;
  if (idx >= tot) return;
  int c = idx >> 11;
  int r = idx & 2047;
  int o = r >> 4, s = r & 15;
  int k = c*16 + s;
  int i = k / KW, kw = k - i*KW;
  float v = w[((size_t)o*Dd + i)*KW + kw];
  if (scale) v *= scale[i];
  unsigned short hi = f2bf(v);
  wp[idx] = hi;
  wp[(size_t)tot + idx] = f2bf(v - bf2f(hi));
}

// folded conv bias: bout[o] = cb[go+o] + sum_i shf[i]*sum_kw w[o][i][kw]
__global__ void k_bfold(float* __restrict__ bout, const float* __restrict__ w,
                        const float* __restrict__ shf, const float* __restrict__ cb,
                        int go, int KW){
  int o = blockIdx.x, i = threadIdx.x;
  float p = 0.f;
  if (shf){
    const float* wr = w + ((size_t)o*Dd + i)*KW;
    float s = 0.f;
    for (int kw=0; kw<KW; kw++) s += wr[kw];
    p = s * shf[i];
  }
  __shared__ float red[128];
  red[i] = p; __syncthreads();
  for (int st=64; st>0; st>>=1){
    if (i<st) red[i] += red[i+st];
    __syncthreads();
  }
  if (i==0) bout[o] = cb[go+o] + red[0];
}

// conv GEMM: A (weights) direct-global fragment loads; B double-buffered LDS,
// one barrier per chunk, register prefetch. BN fold pre-applied.
template<int KW>
__global__ void k_convmfma2(float* __restrict__ y, const float* __restrict__ x,
                            const unsigned short* __restrict__ wp,
                            const float* __restrict__ biasF,
                            int Lout, int XS, int YS){
  const int C = (Dd*KW)/16;
  int b = blockIdx.y;
  int t0 = blockIdx.x*64;
  __shared__ unsigned short Bh[2][64*24], Bl[2][64*24];
  int tid = threadIdx.x;
  int w = tid>>6, l = tid&63, lr = l&31, lg = l>>5;
  int kx = tid&15, tq = tid>>4;
  const unsigned short* wpL = wp + (size_t)C*2048;
  const float* xb = x + (size_t)b*Dd*XS;
  f32x16 acc0={}, acc1={};
  // stage chunk 0
  {
    int i = kx/KW, kw = kx - i*KW;
    const float* xr = xb + (size_t)i*XS + t0 + kw + tq*4;
    #pragma unroll
    for (int j=0;j<4;j++){
      float v = xr[j];
      unsigned short h = f2bf(v);
      Bh[0][(tq*4+j)*24+kx] = h;
      Bl[0][(tq*4+j)*24+kx] = f2bf(v - bf2f(h));
    }
  }
  __syncthreads();
  for (int c=0;c<C;c++){
    int cur = c&1, nxt = cur^1;
    bf16x8 aH = *(const bf16x8*)(wp  + ((size_t)c*128 + w*32+lr)*16 + lg*8);
    bf16x8 aL = *(const bf16x8*)(wpL + ((size_t)c*128 + w*32+lr)*16 + lg*8);
    float pv0=0.f,pv1=0.f,pv2=0.f,pv3=0.f;
    if (c+1<C){
      int k1 = (c+1)*16 + kx;
      int i = k1/KW, kw = k1 - i*KW;
      const float* xr = xb + (size_t)i*XS + t0 + kw + tq*4;
      pv0 = xr[0]; pv1 = xr[1]; pv2 = xr[2]; pv3 = xr[3];
    }
    bf16x8 b0H = *(const bf16x8*)&Bh[cur][lr*24 + lg*8];
    bf16x8 b0L = *(const bf16x8*)&Bl[cur][lr*24 + lg*8];
    bf16x8 b1H = *(const bf16x8*)&Bh[cur][(32+lr)*24 + lg*8];
    bf16x8 b1L = *(const bf16x8*)&Bl[cur][(32+lr)*24 + lg*8];
    acc0 = __builtin_amdgcn_mfma_f32_32x32x16_bf16(aH, b0H, acc0, 0,0,0);
    acc1 = __builtin_amdgcn_mfma_f32_32x32x16_bf16(aH, b1H, acc1, 0,0,0);
    acc0 = __builtin_amdgcn_mfma_f32_32x32x16_bf16(aH, b0L, acc0, 0,0,0);
    acc1 = __builtin_amdgcn_mfma_f32_32x32x16_bf16(aH, b1L, acc1, 0,0,0);
    acc0 = __builtin_amdgcn_mfma_f32_32x32x16_bf16(aL, b0H, acc0, 0,0,0);
    acc1 = __builtin_amdgcn_mfma_f32_32x32x16_bf16(aL, b1H, acc1, 0,0,0);
    if (c+1<C){
      unsigned short h;
      h = f2bf(pv0); Bh[nxt][(tq*4+0)*24+kx]=h; Bl[nxt][(tq*4+0)*24+kx]=f2bf(pv0-bf2f(h));
      h = f2bf(pv1); Bh[nxt][(tq*4+1)*24+kx]=h; Bl[nxt][(tq*4+1)*24+kx]=f2bf(pv1-bf2f(h));
      h = f2bf(pv2); Bh[nxt][(tq*4+2)*24+kx]=h; Bl[nxt][(tq*4+2)*24+kx]=f2bf(pv2-bf2f(h));
      h = f2bf(pv3); Bh[nxt][(tq*4+3)*24+kx]=h; Bl[nxt][(tq*4+3)*24+kx]=f2bf(pv3-bf2f(h));
    }
    __syncthreads();
  }
  int tc = t0 + lr;
  #pragma unroll
  for (int reg=0; reg<16; reg++){
    int row = (reg&3) + 8*(reg>>2) + 4*lg;
    int o = w*32 + row;
    float bias = biasF[o];
    float* yp = y + ((size_t)b*Dd + o)*YS;
    if (tc < Lout)      yp[tc]      = fmaxf(acc0[reg] + bias, 0.f);
    if (tc + 32 < Lout) yp[tc + 32] = fmaxf(acc1[reg] + bias, 0.f);
  }
}

// stats -> scale/shift (BN fold)
__global__ void k_bnc_stats2(float* __restrict__ scale, float* __restrict__ shift,
                             const float* __restrict__ y, int Lout, int YS,
                             const float* __restrict__ g, const float* __restrict__ bb, int go){
  int c = blockIdx.x;
  float s=0.f, ss=0.f;
  int cnt = Bc*Lout;
  for (int i = threadIdx.x; i < cnt; i += blockDim.x){
    int b = i / Lout, t = i - b*Lout;
    float v = y[((size_t)b*Dd+c)*YS + t];
    s += v; ss += v*v;
  }
  __shared__ float rs[256], rss[256];
  rs[threadIdx.x]=s; rss[threadIdx.x]=ss; __syncthreads();
  for (int st=128; st>0; st>>=1){
    if (threadIdx.x<st){ rs[threadIdx.x]+=rs[threadIdx.x+st]; rss[threadIdx.x]+=rss[threadIdx.x+st]; }
    __syncthreads();
  }
  if (threadIdx.x==0){
    float m = rs[0]/cnt; float v = rss[0]/cnt - m*m; if (v<0.f) v=0.f;
    float r = rsqrtf(v+1e-5f);
    float scl = r*g[go+c];
    scale[c] = scl;
    shift[c] = bb[go+c] - m*scl;
  }
}

// ---------------- BAN Gram path ----------------
// q GEMM: fp32 4x4 tile; output stored TRANSPOSED as bf16 hi/lo qT[HKc][LQP],
// tail columns (m>=LQ) zeroed so gram/colsum need no bounds checks.
__global__ void k_qgemm_tile(unsigned short* __restrict__ qTH, unsigned short* __restrict__ qTL,
                             const float* __restrict__ x,
                             const float* __restrict__ W, const float* __restrict__ bias,
                             const float* __restrict__ scale, const float* __restrict__ shift,
                             int gbase){
  int bl = blockIdx.z, b = gbase + bl;
  int m0 = blockIdx.y*64;
  int n0 = blockIdx.x*64;
  __shared__ float As[16][64], Bs[16][64];
  int tid = threadIdx.x;
  int tx = tid & 15, ty = tid >> 4;
  int ldr = tid >> 4, ldc = (tid & 15)*4;
  float acc[4][4] = {};
  for (int k0 = 0; k0 < Dd; k0 += 16){
    int d = k0 + ldr;
    float sc_ = scale[d], sh_ = shift[d];
    const float* xrow = x + ((size_t)b*Dd + d)*S3 + m0 + ldc;
    int mb = m0 + ldc;
    float4 a4;
    a4.x = (mb+0 < LQ) ? xrow[0]*sc_+sh_ : 0.f;
    a4.y = (mb+1 < LQ) ? xrow[1]*sc_+sh_ : 0.f;
    a4.z = (mb+2 < LQ) ? xrow[2]*sc_+sh_ : 0.f;
    a4.w = (mb+3 < LQ) ? xrow[3]*sc_+sh_ : 0.f;
    *(float4*)&As[ldr][ldc] = a4;
    *(float4*)&Bs[ldr][ldc] = *(const float4*)(W + (size_t)d*HKc + n0 + ldc);
    __syncthreads();
    #pragma unroll
    for (int kk=0; kk<16; kk++){
      float a[4], bb[4];
      *(float4*)a  = *(const float4*)&As[kk][ty*4];
      *(float4*)bb = *(const float4*)&Bs[kk][tx*4];
      #pragma unroll
      for (int i=0;i<4;i++)
        #pragma unroll
        for (int j=0;j<4;j++) acc[i][j] += a[i]*bb[j];
    }
    __syncthreads();
  }
  #pragma unroll
  for (int j2=0;j2<4;j2++){
    int n = n0 + tx*4 + j2;
    float bn = bias[n];
    ushort4 sh, sl;
    unsigned short hv[4], lv[4];
    #pragma unroll
    for (int i2=0;i2<4;i2++){
      int m = m0 + ty*4 + i2;
      float v = (m < LQ) ? fmaxf(acc[i2][j2] + bn, 0.f) : 0.f;
      unsigned short h = f2bf(v);
      hv[i2] = h; lv[i2] = f2bf(v - bf2f(h));
    }
    sh.x=hv[0]; sh.y=hv[1]; sh.z=hv[2]; sh.w=hv[3];
    sl.x=lv[0]; sl.y=lv[1]; sl.z=lv[2]; sl.w=lv[3];
    size_t base = ((size_t)bl*HKc + n)*LQP + m0 + ty*4;
    *(ushort4*)(qTH + base) = sh;
    *(ushort4*)(qTL + base) = sl;
  }
}

// colsum over qT rows, split 4-way over K (blockIdx.z); atomicAdd into zeroed S.
__global__ void k_colsum_qT(float* __restrict__ S, const unsigned short* __restrict__ qTH,
                            const unsigned short* __restrict__ qTL, int gbase){
  int j = blockIdx.x*256 + threadIdx.x;
  int bl = blockIdx.y;
  int kq = blockIdx.z;           // 0..3, each covers LQP/4 columns
  if (j >= HKc) return;
  const ushort4* ph = (const ushort4*)(qTH + ((size_t)bl*HKc + j)*LQP) + kq*(LQP/16);
  const ushort4* pl = (const ushort4*)(qTL + ((size_t)bl*HKc + j)*LQP) + kq*(LQP/16);
  float s=0.f;
  for (int t=0;t<LQP/16;t++){
    ushort4 a = ph[t], c = pl[t];
    s += bf2f(a.x)+bf2f(a.y)+bf2f(a.z)+bf2f(a.w);
    s += bf2f(c.x)+bf2f(c.y)+bf2f(c.z)+bf2f(c.w);
  }
  atomicAdd(&S[(gbase+bl)*HKc + j], s);
}

// Gq = q^T q via split-bf16 MFMA. ZERO LDS / ZERO barriers.
// Split-K by 2 (ks): each half does 28 of 56 chunks, atomicAdd into zeroed Gqp.
// graph = blk & 7 keeps one graph per XCD (L2 pinning).
__global__ void k_gramT(float* __restrict__ Gp, const unsigned short* __restrict__ qTH,
                        const unsigned short* __restrict__ qTL, int gbase){
  int blk = blockIdx.x;
  int bl = blk & 7;
  int ks = (blk >> 3) & 1;
  int tl0 = blk >> 4;
  int bg = gbase + bl;
  int tl = tl0; int ti = 0;
  while (tl >= 12-ti){ tl -= 12-ti; ti++; }
  int tj = ti + tl;
  int r0 = ti*64, c0 = tj*64;
  const unsigned short* qH = qTH + (size_t)bl*HKc*LQP;
  const unsigned short* qL = qTL + (size_t)bl*HKc*LQP;
  float* Gb = Gp + ((size_t)bg*NT + tl0)*TSZ;
  int tid = threadIdx.x;
  int w = tid>>6, l = tid&63, lr = l&31, lg = l>>5;
  int mi = w>>1, ni = w&1;
  const unsigned short* aHp = qH + (size_t)(r0 + mi*32 + lr)*LQP + lg*8;
  const unsigned short* aLp = qL + (size_t)(r0 + mi*32 + lr)*LQP + lg*8;
  const unsigned short* bHp = qH + (size_t)(c0 + ni*32 + lr)*LQP + lg*8;
  const unsigned short* bLp = qL + (size_t)(c0 + ni*32 + lr)*LQP + lg*8;
  f32x16 acc = {};
  int cs = ks*28;
  #pragma unroll 4
  for (int c=cs; c<cs+28; c++){
    bf16x8 aH = *(const bf16x8*)(aHp + c*16);
    bf16x8 aL = *(const bf16x8*)(aLp + c*16);
    bf16x8 bH = *(const bf16x8*)(bHp + c*16);
    bf16x8 bL = *(const bf16x8*)(bLp + c*16);
    acc = __builtin_amdgcn_mfma_f32_32x32x16_bf16(aH, bH, acc, 0,0,0);
    acc = __builtin_amdgcn_mfma_f32_32x32x16_bf16(aH, bL, acc, 0,0,0);
    acc = __builtin_amdgcn_mfma_f32_32x32x16_bf16(aL, bH, acc, 0,0,0);
  }
  #pragma unroll
  for (int reg=0; reg<16; reg++){
    int row = (reg&3) + 8*(reg>>2) + 4*lg;
    atomicAdd(&Gb[(size_t)(mi*32+row)*64 + ni*32 + lr], acc[reg]);
  }
}

// ---------------- v side (fp32, proven R6 path) ----------------
__global__ void k_vgemm8(float* __restrict__ v, const float* __restrict__ vd,
                         const float* __restrict__ W, const float* __restrict__ bias){
  int j = blockIdx.x*256 + threadIdx.x;
  int r0 = blockIdx.y*8;
  __shared__ float xr[8][Dd];
  for (int idx=threadIdx.x; idx<8*Dd; idx+=256){
    int r = idx>>7, k = idx&127;
    xr[r][k] = vd[(size_t)(r0 + r)*Dd + k];
  }
  __syncthreads();
  float acc[8];
  float bj = bias[j];
  #pragma unroll
  for (int r=0;r<8;r++) acc[r]=bj;
  for (int k=0;k<Dd;k++){
    float wk = W[(size_t)k*HKc+j];
    #pragma unroll
    for (int r=0;r<8;r++) acc[r] += xr[r][k]*wk;
  }
  #pragma unroll
  for (int r=0;r<8;r++)
    v[(size_t)(r0+r)*HKc + j] = fmaxf(acc[r],0.f);
}

__global__ void k_colsum_v(float* __restrict__ S, const float* __restrict__ X){
  int j = blockIdx.x*blockDim.x + threadIdx.x;
  int bl = blockIdx.y;
  if (j >= HKc) return;
  const float* p = X + (size_t)bl*NPGc*HKc + j;
  float s=0.f;
  for (int t=0;t<NPGc;t++) s += p[(size_t)t*HKc];
  S[bl*HKc + j] = s;
}

// gramf over packed upper-triangle tiles (fp32 4x4, LDS-tiled).
// 1-D grid blk = tl0*32 + bg -> XCD = bg%8: graphs {g,g+8,g+16,g+24} pin to one
// XCD, so each XCD's L2 holds 4 graphs' V (~3.6 MB) and V is fetched ~once.
__global__ void k_gramf_sym(float* __restrict__ f, const float* __restrict__ V,
                            const float* __restrict__ Gp, const float* __restrict__ hm){
  int blk = blockIdx.x;
  int bg = blk & 31;
  int tl0 = blk >> 5;
  int tl = tl0; int ti = 0;
  while (tl >= 12-ti){ tl -= 12-ti; ti++; }
  int tj = ti + tl;
  int r0 = ti*64, c0 = tj*64;
  int offdiag = (ti != tj);
  const float* Vb = V + (size_t)bg*NPGc*HKc;
  __shared__ float As[16][64], Bs[16][64];
  __shared__ float wc[64], wr[64];
  int tid = threadIdx.x;
  int tx = tid & 15, ty = tid >> 4;
  int ldr = tid >> 4, ldc = (tid & 15)*4;
  if (tid < 64) wc[tid] = hm[c0+tid] + hm[HKc + c0 + tid];
  else if (tid < 128) wr[tid-64] = hm[r0+tid-64] + hm[HKc + r0 + tid-64];
  float acc[4][4] = {};
  for (int t0=0; t0<NPGc; t0+=16){
    float4 av = make_float4(0.f,0.f,0.f,0.f), bv4 = make_float4(0.f,0.f,0.f,0.f);
    if (t0+ldr < NPGc){
      const float* row = Vb + (size_t)(t0+ldr)*HKc;
      av  = *(const float4*)(row + r0 + ldc);
      bv4 = *(const float4*)(row + c0 + ldc);
    }
    *(float4*)&As[ldr][ldc] = av;
    *(float4*)&Bs[ldr][ldc] = bv4;
    __syncthreads();
    #pragma unroll
    for (int tt=0; tt<16; tt++){
      float a[4], bb[4];
      *(float4*)a  = *(const float4*)&As[tt][ty*4];
      *(float4*)bb = *(const float4*)&Bs[tt][tx*4];
      #pragma unroll
      for (int i=0;i<4;i++)
        #pragma unroll
        for (int j=0;j<4;j++) acc[i][j] += a[i]*bb[j];
    }
    __syncthreads();
  }
  const float* gqb = Gp + ((size_t)bg*NT + tl0)*TSZ;
  float w0 = wc[tx*4+0], w1 = wc[tx*4+1], w2 = wc[tx*4+2], w3 = wc[tx*4+3];
  float colp[4] = {0.f,0.f,0.f,0.f};
  #pragma unroll
  for (int i=0;i<4;i++){
    int rl = ty*4 + i;
    int r = r0 + rl;
    const float4 g4 = *(const float4*)(gqb + rl*64 + tx*4);
    float s = acc[i][0]*w0*g4.x + acc[i][1]*w1*g4.y
            + acc[i][2]*w2*g4.z + acc[i][3]*w3*g4.w;
    s += __shfl_xor(s, 1); s += __shfl_xor(s, 2);
    s += __shfl_xor(s, 4); s += __shfl_xor(s, 8);
    if (tx==0) atomicAdd(&f[bg*HKc + r], s);
    if (offdiag){
      float wri = wr[rl];
      colp[0] += acc[i][0]*wri*g4.x;
      colp[1] += acc[i][1]*wri*g4.y;
      colp[2] += acc[i][2]*wri*g4.z;
      colp[3] += acc[i][3]*wri*g4.w;
    }
  }
  if (offdiag){
    #pragma unroll
    for (int j=0;j<4;j++){
      colp[j] += __shfl_xor(colp[j], 16);
      colp[j] += __shfl_xor(colp[j], 32);
    }
    if ((tid & 48) == 0){
      #pragma unroll
      for (int j=0;j<4;j++)
        atomicAdd(&f[bg*HKc + c0 + tx*4 + j], colp[j]);
    }
  }
}

// batched pool over 3 views
__global__ void k_pool3(float* __restrict__ fp, const float* __restrict__ f3,
                        const float* __restrict__ Sv3, const float* __restrict__ Sq,
                        const float* __restrict__ hb){
  int idx = blockIdx.x*256 + threadIdx.x;
  if (idx >= 3*Bc*256) return;
  int v = idx >> 13;
  int rem = idx & 8191;
  int b = rem >> 8, c = rem & 255;
  const float* f = f3 + (size_t)v*Bc*HKc;
  const float* Sv = Sv3 + (size_t)v*Bc*HKc;
  float hbs = hb[0] + hb[1];
  float s = 0.f;
  #pragma unroll
  for (int r=0;r<3;r++){
    int k = c*3 + r;
    s += f[b*HKc + k] + hbs*Sv[b*HKc + k]*Sq[b*HKc + k];
  }
  fp[idx] = s;
}

__global__ void k_bnfeat3(float* __restrict__ y, const float* __restrict__ x, const float* __restrict__ g,
                          const float* __restrict__ bb, int C){
  int c = blockIdx.x; int v = blockIdx.y; int b = threadIdx.x;
  __shared__ float buf[32];
  __shared__ float mv[2];
  int row = v*32 + b;
  float val = x[(size_t)row*C + c];
  buf[b] = val;
  __syncthreads();
  if (b == 0){
    float s = 0.f;
    for (int i=0;i<32;i++) s += buf[i];
    float m = s/32.f;
    float vs = 0.f;
    for (int i=0;i<32;i++){ float d = buf[i]-m; vs += d*d; }
    mv[0] = m; mv[1] = vs/32.f;
  }
  __syncthreads();
  y[(size_t)row*C + c] = (val - mv[0])*rsqrtf(mv[1]+1e-5f)*g[c] + bb[c];
}

__global__ void k_mlp(float* __restrict__ out, const float* __restrict__ in, const float* __restrict__ W,
                      const float* __restrict__ bias, int K, int Nc, int doRelu){
  int b = blockIdx.y;
  int j = blockIdx.x*blockDim.x + threadIdx.x;
  __shared__ float xr[512];
  for (int k=threadIdx.x; k<K; k+=blockDim.x) xr[k] = in[(size_t)b*K+k];
  __syncthreads();
  if (j >= Nc) return;
  float s = bias[j];
  for (int k=0;k<K;k++) s += xr[k]*W[(size_t)k*Nc + j];
  if (doRelu) s = fmaxf(s, 0.f);
  out[(size_t)b*Nc + j] = s;
}

__global__ void k_score96(float* __restrict__ sc, const float* __restrict__ h, const float* __restrict__ w,
                          const float* __restrict__ bb){
  int b = threadIdx.x; if (b>=96) return;
  float s = bb[0];
  for (int k=0;k<Dd;k++) s += h[(size_t)b*Dd+k]*w[k];
  sc[b] = s;
}

__global__ void k_out(float* __restrict__ out, const float* __restrict__ scores){
  int t = threadIdx.x;
  __shared__ float loss_s;
  if (t == 0){
    float sn1[32], sn2[32];
    for (int i=0;i<32;i++){
      float a = scores[32+i]; sn1[i] = a / fmaxf(fabsf(a), 1e-12f);
      float c = scores[64+i]; sn2[i] = c / fmaxf(fabsf(c), 1e-12f);
    }
    float acc = 0.f;
    for (int i=0;i<32;i++){
      float mx = -1e30f;
      for (int j=0;j<32;j++) mx = fmaxf(mx, sn1[i]*sn2[j]);
      float se = 0.f;
      for (int j=0;j<32;j++) se += expf(sn1[i]*sn2[j]-mx);
      acc += sn1[i]*sn2[i] - (mx + logf(se));
    }
    loss_s = -acc/32.f;
  }
  __syncthreads();
  out[t*4+0] = scores[t];
  out[t*4+1] = scores[32+t];
  out[t*4+2] = scores[64+t];
  out[t*4+3] = loss_s;
}

extern "C" void kernel_launch(void* const* d_in, const int* in_sizes, int n_in,
                              void* d_out, int out_size, void* d_ws, size_t ws_size,
                              hipStream_t stream){
  static const int exp_sizes[38] = {
    Nn*INFc, Ec, Ec, Bc*LPc, INFc*Dd,
    9*Dd*Dd, 9*Dd, 9*Dd*Dd, 9*Dd,
    26*Dd, Dd*Dd*3, Dd*Dd*6, Dd*Dd*9, 3*Dd, 3*Dd, 3*Dd,
    Dd*HKc, HKc, Dd*HKc, HKc, 2*HKc, 2, 256, 256,
    256*512, 512, 512*512, 512, 512*128, 128, 128, 1,
    512, 512, 512, 512, 128, 128 };
  if (n_in != 38){ k_sentinel<<<1,128,0,stream>>>((float*)d_out, 2000.f + n_in); return; }
  for (int i=0;i<38;i++){
    if (in_sizes[i] != exp_sizes[i]){
      k_sentinel<<<1,128,0,stream>>>((float*)d_out, 1000.f + i); return;
    }
  }

  const float* node_h=(const float*)d_in[0];
  const int*  esrc  =(const int*)d_in[1];
  const int*  edst  =(const int*)d_in[2];
  const int*  vp    =(const int*)d_in[3];
  const float* W_init=(const float*)d_in[4];
  const float* gcn_W =(const float*)d_in[5];
  const float* gcn_b =(const float*)d_in[6];
  const float* gcn_Wr=(const float*)d_in[7];
  const float* gcn_br=(const float*)d_in[8];
  const float* emb   =(const float*)d_in[9];
  const float* c1w=(const float*)d_in[10];
  const float* c2w=(const float*)d_in[11];
  const float* c3w=(const float*)d_in[12];
  const float* cbv=(const float*)d_in[13];
  const float* bng=(const float*)d_in[14];
  const float* bnb=(const float*)d_in[15];
  const float* Wv =(const float*)d_in[16];
  const float* bvv=(const float*)d_in[17];
  const float* Wq =(const float*)d_in[18];
  const float* bq =(const float*)d_in[19];
  const float* hmat =(const float*)d_in[20];
  const float* hbias=(const float*)d_in[21];
  const float* bang =(const float*)d_in[22];
  const float* banb =(const float*)d_in[23];
  const float* mw1=(const float*)d_in[24]; const float* mb1=(const float*)d_in[25];
  const float* mw2=(const float*)d_in[26]; const float* mb2=(const float*)d_in[27];
  const float* mw3=(const float*)d_in[28]; const float* mb3=(const float*)d_in[29];
  const float* mw4=(const float*)d_in[30]; const float* mb4=(const float*)d_in[31];
  const float* g1=(const float*)d_in[32]; const float* bb1=(const float*)d_in[33];
  const float* g2=(const float*)d_in[34]; const float* bb2=(const float*)d_in[35];
  const float* g3=(const float*)d_in[36]; const float* bb3=(const float*)d_in[37];

  float* ws = (float*)d_ws;
  size_t off = 0;
  auto alloc = [&](size_t n){ float* p = ws + off; off += n; return p; };

  const size_t NDsz = (size_t)Nn*Dd;              // 1,187,840
  const size_t CNNBP = (size_t)Bc*Dd*S1;          // 3,702,784
  const size_t ADJ  = (size_t)Bc*NPGc*NPGc;       // 2,691,200
  const size_t QTF  = (size_t)8*HKc*LQP;          // qT hi+lo as float-slots: 5,505,024
  const size_t VB   = (size_t)Bc*NPGc*HKc;        // 7,127,040
  const size_t AGGF = (size_t)3*Nn*Dd;            // agg hi+lo as float-slots: 3,563,520
  size_t ARENA = 7*NDsz + ADJ + AGGF;             // 14,569,600
  if (ARENA < 4*NDsz + VB) ARENA = 4*NDsz + VB;   // 11,878,400
  if (ARENA < CNNBP + QTF) ARENA = CNNBP + QTF;
  if (ARENA < 2*CNNBP) ARENA = 2*CNNBP;

  // smalls
  float* Sq   = alloc((size_t)Bc*HKc);
  float* Sv3  = alloc((size_t)3*Bc*HKc);
  float* fbuf3= alloc((size_t)3*Bc*HKc);
  float* fpool3=alloc((size_t)3*Bc*256);
  float* hh1  = alloc((size_t)96*512);
  float* hh2  = alloc((size_t)96*512);
  float* hh3  = alloc((size_t)96*128);
  float* sc   = alloc(96);
  float* scl1 = alloc(128); float* shf1 = alloc(128);
  float* scl2 = alloc(128); float* shf2 = alloc(128);
  float* scl3 = alloc(128); float* shf3 = alloc(128);
  float* b1f  = alloc(128); float* b2f  = alloc(128); float* b3f = alloc(128);
  // fragment-packed conv weights (hi+lo): KT*128 float-slots each
  unsigned short* wp1 = (unsigned short*)alloc((size_t)384*128);
  unsigned short* wp2 = (unsigned short*)alloc((size_t)768*128);
  unsigned short* wp3 = (unsigned short*)alloc((size_t)1152*128);
  // GCN weights fragment-packed (hi+lo)
  unsigned short* WTs  = (unsigned short*)alloc(147456);
  unsigned short* WrTs = (unsigned short*)alloc(147456);
  float* Gqp = alloc((size_t)Bc*NT*TSZ);          // packed triangle: 10,223,616
  float* arena = alloc(ARENA);

  // phase views
  float* cnnA = arena;                  // CNN out (S3-padded) lives here
  float* cnnB = arena + CNNBP;
  float* qbuf = arena + CNNBP;          // qT as bf16 hi/lo (QTF float-slots)
  unsigned short* qTH = (unsigned short*)qbuf;
  unsigned short* qTL = qTH + (size_t)8*HKc*LQP;
  float* h0b  = arena;                  // [0, NDsz)
  float* Bb   = arena + NDsz;           // 3 bufs [NDsz, 4*NDsz)
  float* Cb   = arena + 4*NDsz;         // 3 bufs [4N, 7N)
  float* Adj  = arena + 7*NDsz;         // [7N, 7N+ADJ)
  unsigned short* aggH = (unsigned short*)(arena + 7*NDsz + ADJ);
  unsigned short* aggL = aggH + (size_t)3*Nn*Dd;
  float* vbuf = arena + 4*NDsz;         // BAN phase: fp32 V [4N, 4N+VB)

  // ---- prepacks (layer-1 conv weights need no BN fold) ----
  k_wpack16<<<(24*2048+255)/256,256,0,stream>>>(wp1, c1w, nullptr, 3, 24);
  k_bfold<<<128,128,0,stream>>>(b1f, c1w, nullptr, cbv, 0, 3);
  k_wsplit<<<(9*Dd*Dd+255)/256,256,0,stream>>>(WTs, WrTs, gcn_W, gcn_Wr);

  // ---- ProteinCNN (BN folded into weights/bias of the NEXT conv) ----
  k_embed<<<dim3((LPc+127)/128, Dd, Bc),128,0,stream>>>(cnnB, vp, emb);
  k_convmfma2<3><<<dim3(15,Bc),256,0,stream>>>(cnnA, cnnB, wp1, b1f, 898, 900, S1);
  k_bnc_stats2<<<Dd,256,0,stream>>>(scl1, shf1, cnnA, 898, S1, bng, bnb, 0);
  k_wpack16<<<(48*2048+255)/256,256,0,stream>>>(wp2, c2w, scl1, 6, 48);
  k_bfold<<<128,128,0,stream>>>(b2f, c2w, shf1, cbv, 128, 6);
  k_convmfma2<6><<<dim3(14,Bc),256,0,stream>>>(cnnB, cnnA, wp2, b2f, 893, S1, S2);
  k_bnc_stats2<<<Dd,256,0,stream>>>(scl2, shf2, cnnB, 893, S2, bng, bnb, 128);
  k_wpack16<<<(72*2048+255)/256,256,0,stream>>>(wp3, c3w, scl2, 9, 72);
  k_bfold<<<128,128,0,stream>>>(b3f, c3w, shf2, cbv, 256, 9);
  k_convmfma2<9><<<dim3(14,Bc),256,0,stream>>>(cnnA, cnnB, wp3, b3f, 885, S2, S3);
  k_bnc_stats2<<<Dd,256,0,stream>>>(scl3, shf3, cnnA, 885, S3, bng, bnb, 256);

  // ---- q branch: 4 passes of 8 graphs; qT stored bf16 hi/lo; split-K MFMA gram ----
  hipMemsetAsync(Sq, 0, (size_t)Bc*HKc*sizeof(float), stream);
  for (int gb = 0; gb < Bc; gb += 8){
    k_qgemm_tile<<<dim3(12,LQP/64,8),256,0,stream>>>(qTH, qTL, cnnA, Wq, bq, scl3, shf3, gb);
    k_colsum_qT<<<dim3(3,8,4),256,0,stream>>>(Sq, qTH, qTL, gb);
    hipMemsetAsync(Gqp + (size_t)gb*NT*TSZ, 0, (size_t)8*NT*TSZ*sizeof(float), stream);
    k_gramT<<<NT*16,256,0,stream>>>(Gqp, qTH, qTL, gb);
  }

  // ---- dense adjacency ----
  hipMemsetAsync(Adj, 0, ADJ*sizeof(float), stream);
  k_build_adj<<<(Ec+255)/256,256,0,stream>>>(Adj, esrc, edst);

  hipMemsetAsync(fbuf3, 0, (size_t)3*Bc*HKc*sizeof(float), stream);

  // ---- GCN: h0 once, then per layer: MFMA agg + MFMA fused linear ----
  k_h0<<<Nn,Dd,0,stream>>>(h0b, node_h, W_init);
  k_aggm<<<dim3(5,Bc,3),256,0,stream>>>(aggH, aggL, h0b, 0, Adj);
  k_gcnlin<<<dim3(145,3),256,0,stream>>>(Bb, NDsz, aggH, aggL, h0b, 0, WTs, WrTs, gcn_b, gcn_br, 0);
  k_aggm<<<dim3(5,Bc,3),256,0,stream>>>(aggH, aggL, Bb, NDsz, Adj);
  k_gcnlin<<<dim3(145,3),256,0,stream>>>(Cb, NDsz, aggH, aggL, Bb, NDsz, WTs, WrTs, gcn_b, gcn_br, 1);
  k_aggm<<<dim3(5,Bc,3),256,0,stream>>>(aggH, aggL, Cb, NDsz, Adj);
  k_gcnlin<<<dim3(145,3),256,0,stream>>>(Bb, NDsz, aggH, aggL, Cb, NDsz, WTs, WrTs, gcn_b, gcn_br, 2);

  // ---- BAN per view (fp32 v path; gramf with graph->XCD pinning) ----
  for (int g=0; g<3; g++){
    k_vgemm8<<<dim3(3,(Bc*NPGc)/8),256,0,stream>>>(vbuf, Bb + (size_t)g*NDsz, Wv, bvv);
    k_colsum_v<<<dim3(3,Bc),256,0,stream>>>(Sv3 + (size_t)g*Bc*HKc, vbuf);
    k_gramf_sym<<<NT*32,256,0,stream>>>(fbuf3 + (size_t)g*Bc*HKc, vbuf, Gqp, hmat);
  }

  // ---- batched tail over 3 views (96 rows) ----
  k_pool3<<<(3*Bc*256+255)/256,256,0,stream>>>(fpool3, fbuf3, Sv3, Sq, hbias);
  k_bnfeat3<<<dim3(256,3),32,0,stream>>>(fpool3, fpool3, bang, banb, 256);
  k_mlp<<<dim3(2,96),256,0,stream>>>(hh1, fpool3, mw1, mb1, 256, 512, 1);
  k_bnfeat3<<<dim3(512,3),32,0,stream>>>(hh1, hh1, g1, bb1, 512);
  k_mlp<<<dim3(2,96),256,0,stream>>>(hh2, hh1, mw2, mb2, 512, 512, 1);
  k_bnfeat3<<<dim3(512,3),32,0,stream>>>(hh2, hh2, g2, bb2, 512);
  k_mlp<<<dim3(1,96),256,0,stream>>>(hh3, hh2, mw3, mb3, 512, 128, 1);
  k_bnfeat3<<<dim3(128,3),32,0,stream>>>(hh3, hh3, g3, bb3, 128);
  k_score96<<<1,96,0,stream>>>(sc, hh3, mw4, mb4);
  k_out<<<1,32,0,stream>>>((float*)d_out, sc);
}

// Round 12
// 1623.472 us; speedup vs baseline: 1.0246x; 1.0246x over previous
//
#include <hip/hip_runtime.h>
#include <hip/hip_bf16.h>

#define Bc 32
#define NPGc 290
#define Nn 9280
#define Ec 74240
#define LPc 900
#define INFc 75
#define Dd 128
#define HKc 768
#define LQ 885
#define LQP 896        // LQ padded to /16 (tail zeroed in qT)
#define S1 904
#define S2 896
#define S3 888
#define NT 78          // upper-triangle 64x64 tiles of 768x768
#define TSZ 4096       // 64*64

typedef __attribute__((ext_vector_type(8))) short bf16x8;
typedef __attribute__((ext_vector_type(16))) float f32x16;

static __device__ __forceinline__ unsigned short f2bf(float v){
  unsigned int u = __float_as_uint(v);
  unsigned int r = u + 0x7FFFu + ((u >> 16) & 1u);
  return (unsigned short)(r >> 16);
}
static __device__ __forceinline__ float bf2f(unsigned short b){
  return __uint_as_float(((unsigned int)b) << 16);
}

__global__ void k_sentinel(float* out, float val){
  int t = threadIdx.x;
  if (t < 128) out[t] = val;
}

// ---------------- GCN ----------------
__global__ void k_h0(float* __restrict__ h0, const float* __restrict__ nh, const float* __restrict__ Wi){
  int n = blockIdx.x, j = threadIdx.x;
  __shared__ float arow[INFc];
  if (j < INFc) arow[j] = nh[(size_t)n*INFc + j];
  __syncthreads();
  float s = 0.f;
  #pragma unroll 5
  for (int k=0;k<INFc;k++) s += arow[k]*Wi[(size_t)k*Dd + j];
  h0[(size_t)n*Dd + j] = s;
}

__global__ void k_build_adj(float* __restrict__ A, const int* __restrict__ src, const int* __restrict__ dst){
  int e = blockIdx.x*blockDim.x + threadIdx.x;
  if (e >= Ec) return;
  int s = src[e], d = dst[e];
  int b = d / NPGc;
  int dl = d - b*NPGc, sl = s - b*NPGc;
  atomicAdd(&A[((size_t)b*NPGc + dl)*NPGc + sl], 1.f);
}

// pre-transpose+split GCN weights into fragment-ready layout:
// dst[gl][chunk c][j'][16 kslot], hi at [0,NW), lo at [NW,2NW)
__global__ void k_wsplit(unsigned short* __restrict__ dstW, unsigned short* __restrict__ dstWr,
                         const float* __restrict__ W, const float* __restrict__ Wr){
  int idx = blockIdx.x*256 + threadIdx.x;   // over 9*128*128
  if (idx >= 9*Dd*Dd) return;
  int gl = idx >> 14;
  int r  = idx & 16383;
  int k  = r >> 7, j = r & 127;
  int c = k >> 4, slot = k & 15;
  size_t o = ((((size_t)gl*8 + c)*Dd + j) << 4) + slot;
  const size_t NW = (size_t)9*8*Dd*16;
  float v = W[idx];
  unsigned short hi = f2bf(v);
  dstW[o] = hi; dstW[NW + o] = f2bf(v - bf2f(hi));
  float u = Wr[idx];
  unsigned short hr = f2bf(u);
  dstWr[o] = hr; dstWr[NW + o] = f2bf(u - bf2f(hr));
}

// split W [128][768] into fragment-ready layout [c][j][16slot], hi/lo
__global__ void k_wsplitV(unsigned short* __restrict__ dst, const float* __restrict__ W){
  int idx = blockIdx.x*256 + threadIdx.x;   // over 128*768
  if (idx >= Dd*HKc) return;
  int k = idx / HKc, j = idx - k*HKc;
  int c = k >> 4, slot = k & 15;
  size_t o = (((size_t)c*HKc + j) << 4) + slot;
  const size_t NWv = (size_t)8*HKc*16;
  float v = W[idx];
  unsigned short hi = f2bf(v);
  dst[o] = hi; dst[NWv + o] = f2bf(v - bf2f(hi));
}

// agg = A @ h via MFMA. A exact in bf16 (integer counts). h split hi/lo at stage.
__global__ void k_aggm(unsigned short* __restrict__ aggH, unsigned short* __restrict__ aggL,
                       const float* __restrict__ inb, size_t istride,
                       const float* __restrict__ Adj){
  int g = blockIdx.z, b = blockIdx.y;
  int i0 = blockIdx.x*64;
  const float* h = inb + (size_t)g*istride + (size_t)b*NPGc*Dd;
  const float* Ab = Adj + (size_t)b*NPGc*NPGc;
  __shared__ unsigned short Bh[128*24], Bl[128*24];
  int tid = threadIdx.x;
  int w = tid>>6, l = tid&63, lr = l&31, lg = l>>5;
  int mh = w>>1, nh = w&1;
  int kr = tid>>4, jq = tid&15;
  f32x16 acc0={}, acc1={};
  for (int c=0;c<19;c++){
    int k0 = c*16;
    {
      int ci = k0 + kr;
      if (ci < NPGc){
        const float* hr_ = h + (size_t)ci*Dd + jq*8;
        #pragma unroll
        for (int m=0;m<8;m++){
          float v = hr_[m];
          unsigned short hi16 = f2bf(v);
          Bh[(jq*8+m)*24 + kr] = hi16;
          Bl[(jq*8+m)*24 + kr] = f2bf(v - bf2f(hi16));
        }
      } else {
        #pragma unroll
        for (int m=0;m<8;m++){ Bh[(jq*8+m)*24+kr]=0; Bl[(jq*8+m)*24+kr]=0; }
      }
    }
    __syncthreads();
    int row = i0 + mh*32 + lr;
    bf16x8 aA = {0,0,0,0,0,0,0,0};
    if (row < NPGc && k0+15 < NPGc){
      const float* ar_ = Ab + (size_t)row*NPGc + k0 + lg*8;
      #pragma unroll
      for (int m=0;m<8;m++) aA[m] = (short)f2bf(ar_[m]);
    } else if (row < NPGc){
      #pragma unroll
      for (int m=0;m<8;m++){
        int k = k0 + lg*8 + m;
        aA[m] = (short)((k < NPGc) ? f2bf(Ab[(size_t)row*NPGc + k]) : 0);
      }
    }
    bf16x8 b0H = *(const bf16x8*)&Bh[(nh*64+lr)*24 + lg*8];
    bf16x8 b0L = *(const bf16x8*)&Bl[(nh*64+lr)*24 + lg*8];
    bf16x8 b1H = *(const bf16x8*)&Bh[(nh*64+32+lr)*24 + lg*8];
    bf16x8 b1L = *(const bf16x8*)&Bl[(nh*64+32+lr)*24 + lg*8];
    acc0 = __builtin_amdgcn_mfma_f32_32x32x16_bf16(aA, b0H, acc0, 0, 0, 0);
    acc0 = __builtin_amdgcn_mfma_f32_32x32x16_bf16(aA, b0L, acc0, 0, 0, 0);
    acc1 = __builtin_amdgcn_mfma_f32_32x32x16_bf16(aA, b1H, acc1, 0, 0, 0);
    acc1 = __builtin_amdgcn_mfma_f32_32x32x16_bf16(aA, b1L, acc1, 0, 0, 0);
    __syncthreads();
  }
  size_t gb = ((size_t)g*Bc + b)*NPGc;
  int j0 = nh*64 + lr;
  #pragma unroll
  for (int reg=0; reg<16; reg++){
    int rowl = (reg&3) + 8*(reg>>2) + 4*lg;
    int i = i0 + mh*32 + rowl;
    if (i < NPGc){
      size_t base = (gb + i)*Dd;
      float v0 = acc0[reg];
      unsigned short h0_ = f2bf(v0);
      aggH[base + j0] = h0_;
      aggL[base + j0] = f2bf(v0 - bf2f(h0_));
      float v1 = acc1[reg];
      unsigned short h1_ = f2bf(v1);
      aggH[base + j0 + 32] = h1_;
      aggL[base + j0 + 32] = f2bf(v1 - bf2f(h1_));
    }
  }
}

// out = relu(agg@W + b) + relu(h@Wr + br). No LDS/barriers.
__global__ void k_gcnlin(float* __restrict__ outb, size_t ostride,
                         const unsigned short* __restrict__ aggH, const unsigned short* __restrict__ aggL,
                         const float* __restrict__ inb, size_t istride,
                         const unsigned short* __restrict__ WTs, const unsigned short* __restrict__ WrTs,
                         const float* __restrict__ ball, const float* __restrict__ brall, int lno){
  int g = blockIdx.y;
  int m0 = blockIdx.x*64;
  int gl = g*3 + lno;
  const size_t NW = (size_t)9*8*Dd*16;
  int tid = threadIdx.x;
  int w=tid>>6, l=tid&63, lr=l&31, lg=l>>5;
  int mh=w>>1, nh=w&1;
  const float* hin = inb + (size_t)g*istride;
  const unsigned short* agH = aggH + (size_t)g*Nn*Dd;
  const unsigned short* agL = aggL + (size_t)g*Nn*Dd;
  f32x16 aw0={},aw1={},ar0={},ar1={};
  int row = m0 + mh*32 + lr;
  for (int c=0;c<8;c++){
    int k0 = c*16;
    bf16x8 gH = *(const bf16x8*)&agH[(size_t)row*Dd + k0 + lg*8];
    bf16x8 gL = *(const bf16x8*)&agL[(size_t)row*Dd + k0 + lg*8];
    bf16x8 hH, hL;
    {
      const float* hp = hin + (size_t)row*Dd + k0 + lg*8;
      #pragma unroll
      for (int m=0;m<8;m++){
        float v = hp[m];
        unsigned short x = f2bf(v);
        hH[m] = (short)x;
        hL[m] = (short)f2bf(v - bf2f(x));
      }
    }
    size_t wb0 = ((((size_t)gl*8 + c)*Dd) + nh*64 + lr)*16 + (size_t)lg*8;
    size_t wb1 = wb0 + 32*16;
    bf16x8 w0H = *(const bf16x8*)&WTs[wb0];
    bf16x8 w0L = *(const bf16x8*)&WTs[NW + wb0];
    bf16x8 w1H = *(const bf16x8*)&WTs[wb1];
    bf16x8 w1L = *(const bf16x8*)&WTs[NW + wb1];
    bf16x8 r0H = *(const bf16x8*)&WrTs[wb0];
    bf16x8 r0L = *(const bf16x8*)&WrTs[NW + wb0];
    bf16x8 r1H = *(const bf16x8*)&WrTs[wb1];
    bf16x8 r1L = *(const bf16x8*)&WrTs[NW + wb1];
    aw0 = __builtin_amdgcn_mfma_f32_32x32x16_bf16(gH, w0H, aw0, 0,0,0);
    aw0 = __builtin_amdgcn_mfma_f32_32x32x16_bf16(gH, w0L, aw0, 0,0,0);
    aw0 = __builtin_amdgcn_mfma_f32_32x32x16_bf16(gL, w0H, aw0, 0,0,0);
    aw1 = __builtin_amdgcn_mfma_f32_32x32x16_bf16(gH, w1H, aw1, 0,0,0);
    aw1 = __builtin_amdgcn_mfma_f32_32x32x16_bf16(gH, w1L, aw1, 0,0,0);
    aw1 = __builtin_amdgcn_mfma_f32_32x32x16_bf16(gL, w1H, aw1, 0,0,0);
    ar0 = __builtin_amdgcn_mfma_f32_32x32x16_bf16(hH, r0H, ar0, 0,0,0);
    ar0 = __builtin_amdgcn_mfma_f32_32x32x16_bf16(hH, r0L, ar0, 0,0,0);
    ar0 = __builtin_amdgcn_mfma_f32_32x32x16_bf16(hL, r0H, ar0, 0,0,0);
    ar1 = __builtin_amdgcn_mfma_f32_32x32x16_bf16(hH, r1H, ar1, 0,0,0);
    ar1 = __builtin_amdgcn_mfma_f32_32x32x16_bf16(hH, r1L, ar1, 0,0,0);
    ar1 = __builtin_amdgcn_mfma_f32_32x32x16_bf16(hL, r1H, ar1, 0,0,0);
  }
  float* out = outb + (size_t)g*ostride;
  int j0 = nh*64 + lr;
  float b0 = ball[gl*Dd + j0], b1 = ball[gl*Dd + j0 + 32];
  float c0 = brall[gl*Dd + j0], c1 = brall[gl*Dd + j0 + 32];
  #pragma unroll
  for (int reg=0; reg<16; reg++){
    int rowl = (reg&3)+8*(reg>>2)+4*lg;
    int i = m0 + mh*32 + rowl;
    out[(size_t)i*Dd + j0]      = fmaxf(aw0[reg]+b0,0.f) + fmaxf(ar0[reg]+c0,0.f);
    out[(size_t)i*Dd + j0 + 32] = fmaxf(aw1[reg]+b1,0.f) + fmaxf(ar1[reg]+c1,0.f);
  }
}

// ---------------- ProteinCNN ----------------
__global__ void k_embed(float* __restrict__ x, const int* __restrict__ vp, const float* __restrict__ emb){
  int t = blockIdx.x*blockDim.x + threadIdx.x;
  int d = blockIdx.y, b = blockIdx.z;
  if (t >= LPc) return;
  int tok = vp[b*LPc + t];
  x[((size_t)b*Dd + d)*LPc + t] = emb[(size_t)tok*Dd + d];
}

// pack conv weights (BN scale folded in) fragment-ready: hi[(c*128+o)*16+s], lo at +C*2048
__global__ void k_wpack16(unsigned short* __restrict__ wp, const float* __restrict__ w,
                          const float* __restrict__ scale, int KW, int C){
  int idx = blockIdx.x*256 + threadIdx.x;
  int tot = C*2048;
  if (idx >= tot) return;
  int c = idx >> 11;
  int r = idx & 2047;
  int o = r >> 4, s = r & 15;
  int k = c*16 + s;
  int i = k / KW, kw = k - i*KW;
  float v = w[((size_t)o*Dd + i)*KW + kw];
  if (scale) v *= scale[i];
  unsigned short hi = f2bf(v);
  wp[idx] = hi;
  wp[(size_t)tot + idx] = f2bf(v - bf2f(hi));
}

// folded conv bias: bout[o] = cb[go+o] + sum_i shf[i]*sum_kw w[o][i][kw]
__global__ void k_bfold(float* __restrict__ bout, const float* __restrict__ w,
                        const float* __restrict__ shf, const float* __restrict__ cb,
                        int go, int KW){
  int o = blockIdx.x, i = threadIdx.x;
  float p = 0.f;
  if (shf){
    const float* wr = w + ((size_t)o*Dd + i)*KW;
    float s = 0.f;
    for (int kw=0; kw<KW; kw++) s += wr[kw];
    p = s * shf[i];
  }
  __shared__ float red[128];
  red[i] = p; __syncthreads();
  for (int st=64; st>0; st>>=1){
    if (i<st) red[i] += red[i+st];
    __syncthreads();
  }
  if (i==0) bout[o] = cb[go+o] + red[0];
}

// conv GEMM: A (weights) direct-global fragment loads; B double-buffered LDS,
// one barrier per chunk, register prefetch. BN fold pre-applied.
template<int KW>
__global__ void k_convmfma2(float* __restrict__ y, const float* __restrict__ x,
                            const unsigned short* __restrict__ wp,
                            const float* __restrict__ biasF,
                            int Lout, int XS, int YS){
  const int C = (Dd*KW)/16;
  int b = blockIdx.y;
  int t0 = blockIdx.x*64;
  __shared__ unsigned short Bh[2][64*24], Bl[2][64*24];
  int tid = threadIdx.x;
  int w = tid>>6, l = tid&63, lr = l&31, lg = l>>5;
  int kx = tid&15, tq = tid>>4;
  const unsigned short* wpL = wp + (size_t)C*2048;
  const float* xb = x + (size_t)b*Dd*XS;
  f32x16 acc0={}, acc1={};
  // stage chunk 0
  {
    int i = kx/KW, kw = kx - i*KW;
    const float* xr = xb + (size_t)i*XS + t0 + kw + tq*4;
    #pragma unroll
    for (int j=0;j<4;j++){
      float v = xr[j];
      unsigned short h = f2bf(v);
      Bh[0][(tq*4+j)*24+kx] = h;
      Bl[0][(tq*4+j)*24+kx] = f2bf(v - bf2f(h));
    }
  }
  __syncthreads();
  for (int c=0;c<C;c++){
    int cur = c&1, nxt = cur^1;
    bf16x8 aH = *(const bf16x8*)(wp  + ((size_t)c*128 + w*32+lr)*16 + lg*8);
    bf16x8 aL = *(const bf16x8*)(wpL + ((size_t)c*128 + w*32+lr)*16 + lg*8);
    float pv0=0.f,pv1=0.f,pv2=0.f,pv3=0.f;
    if (c+1<C){
      int k1 = (c+1)*16 + kx;
      int i = k1/KW, kw = k1 - i*KW;
      const float* xr = xb + (size_t)i*XS + t0 + kw + tq*4;
      pv0 = xr[0]; pv1 = xr[1]; pv2 = xr[2]; pv3 = xr[3];
    }
    bf16x8 b0H = *(const bf16x8*)&Bh[cur][lr*24 + lg*8];
    bf16x8 b0L = *(const bf16x8*)&Bl[cur][lr*24 + lg*8];
    bf16x8 b1H = *(const bf16x8*)&Bh[cur][(32+lr)*24 + lg*8];
    bf16x8 b1L = *(const bf16x8*)&Bl[cur][(32+lr)*24 + lg*8];
    acc0 = __builtin_amdgcn_mfma_f32_32x32x16_bf16(aH, b0H, acc0, 0,0,0);
    acc1 = __builtin_amdgcn_mfma_f32_32x32x16_bf16(aH, b1H, acc1, 0,0,0);
    acc0 = __builtin_amdgcn_mfma_f32_32x32x16_bf16(aH, b0L, acc0, 0,0,0);
    acc1 = __builtin_amdgcn_mfma_f32_32x32x16_bf16(aH, b1L, acc1, 0,0,0);
    acc0 = __builtin_amdgcn_mfma_f32_32x32x16_bf16(aL, b0H, acc0, 0,0,0);
    acc1 = __builtin_amdgcn_mfma_f32_32x32x16_bf16(aL, b1H, acc1, 0,0,0);
    if (c+1<C){
      unsigned short h;
      h = f2bf(pv0); Bh[nxt][(tq*4+0)*24+kx]=h; Bl[nxt][(tq*4+0)*24+kx]=f2bf(pv0-bf2f(h));
      h = f2bf(pv1); Bh[nxt][(tq*4+1)*24+kx]=h; Bl[nxt][(tq*4+1)*24+kx]=f2bf(pv1-bf2f(h));
      h = f2bf(pv2); Bh[nxt][(tq*4+2)*24+kx]=h; Bl[nxt][(tq*4+2)*24+kx]=f2bf(pv2-bf2f(h));
      h = f2bf(pv3); Bh[nxt][(tq*4+3)*24+kx]=h; Bl[nxt][(tq*4+3)*24+kx]=f2bf(pv3-bf2f(h));
    }
    __syncthreads();
  }
  int tc = t0 + lr;
  #pragma unroll
  for (int reg=0; reg<16; reg++){
    int row = (reg&3) + 8*(reg>>2) + 4*lg;
    int o = w*32 + row;
    float bias = biasF[o];
    float* yp = y + ((size_t)b*Dd + o)*YS;
    if (tc < Lout)      yp[tc]      = fmaxf(acc0[reg] + bias, 0.f);
    if (tc + 32 < Lout) yp[tc + 32] = fmaxf(acc1[reg] + bias, 0.f);
  }
}

// stats -> scale/shift (BN fold)
__global__ void k_bnc_stats2(float* __restrict__ scale, float* __restrict__ shift,
                             const float* __restrict__ y, int Lout, int YS,
                             const float* __restrict__ g, const float* __restrict__ bb, int go){
  int c = blockIdx.x;
  float s=0.f, ss=0.f;
  int cnt = Bc*Lout;
  for (int i = threadIdx.x; i < cnt; i += blockDim.x){
    int b = i / Lout, t = i - b*Lout;
    float v = y[((size_t)b*Dd+c)*YS + t];
    s += v; ss += v*v;
  }
  __shared__ float rs[256], rss[256];
  rs[threadIdx.x]=s; rss[threadIdx.x]=ss; __syncthreads();
  for (int st=128; st>0; st>>=1){
    if (threadIdx.x<st){ rs[threadIdx.x]+=rs[threadIdx.x+st]; rss[threadIdx.x]+=rss[threadIdx.x+st]; }
    __syncthreads();
  }
  if (threadIdx.x==0){
    float m = rs[0]/cnt; float v = rss[0]/cnt - m*m; if (v<0.f) v=0.f;
    float r = rsqrtf(v+1e-5f);
    float scl = r*g[go+c];
    scale[c] = scl;
    shift[c] = bb[go+c] - m*scl;
  }
}

// ---------------- BAN Gram path ----------------
// qT = relu(x^T @ Wq + bq)^T via split-bf16 MFMA. x is [Dd][S3] (BN fold at stage);
// Wq fragment-packed (A-side); x chunk transposed into LDS hi/lo (B-side).
// Output written directly to qT[HKc][LQP] bf16 hi/lo (coalesced: C/D col = t).
// t >= LQ forced to zero.
__global__ void k_qgemmT(unsigned short* __restrict__ qTH, unsigned short* __restrict__ qTL,
                         const float* __restrict__ x, const unsigned short* __restrict__ WqTs,
                         const float* __restrict__ bias,
                         const float* __restrict__ scale, const float* __restrict__ shift,
                         int gbase){
  int bl = blockIdx.z, b = gbase + bl;
  int t0 = blockIdx.y*64;
  int n0 = blockIdx.x*64;
  const size_t NWv = (size_t)8*HKc*16;
  __shared__ unsigned short Bh[64*24], Bl[64*24];
  int tid = threadIdx.x;
  int w = tid>>6, l = tid&63, lr = l&31, lg = l>>5;
  int mi = w>>1, ni = w&1;
  int kr = tid>>4, jq = tid&15;
  f32x16 acc = {};
  for (int c=0;c<8;c++){
    // stage x chunk [16 d][64 t] -> LDS [t][dslot], BN fold + hi/lo split
    {
      int d = c*16 + kr;
      float sc_ = scale[d], sh_ = shift[d];
      const float* xr = x + ((size_t)b*Dd + d)*S3 + t0 + jq*4;
      #pragma unroll
      for (int m=0;m<4;m++){
        int t = t0 + jq*4 + m;
        float v = (t < LQ) ? xr[m]*sc_ + sh_ : 0.f;
        unsigned short h = f2bf(v);
        Bh[(jq*4+m)*24 + kr] = h;
        Bl[(jq*4+m)*24 + kr] = f2bf(v - bf2f(h));
      }
    }
    __syncthreads();
    size_t wb = (((size_t)c*HKc + n0 + mi*32 + lr) << 4) + lg*8;
    bf16x8 wH = *(const bf16x8*)&WqTs[wb];
    bf16x8 wL = *(const bf16x8*)&WqTs[NWv + wb];
    bf16x8 xH = *(const bf16x8*)&Bh[(ni*32+lr)*24 + lg*8];
    bf16x8 xL = *(const bf16x8*)&Bl[(ni*32+lr)*24 + lg*8];
    acc = __builtin_amdgcn_mfma_f32_32x32x16_bf16(wH, xH, acc, 0,0,0);
    acc = __builtin_amdgcn_mfma_f32_32x32x16_bf16(wH, xL, acc, 0,0,0);
    acc = __builtin_amdgcn_mfma_f32_32x32x16_bf16(wL, xH, acc, 0,0,0);
    __syncthreads();
  }
  int tg = t0 + ni*32 + lr;
  bool tok = tg < LQ;
  #pragma unroll
  for (int reg=0; reg<16; reg++){
    int rowl = (reg&3) + 8*(reg>>2) + 4*lg;
    int n = n0 + mi*32 + rowl;
    float v = tok ? fmaxf(acc[reg] + bias[n], 0.f) : 0.f;
    unsigned short h = f2bf(v);
    size_t o = ((size_t)bl*HKc + n)*LQP + tg;
    qTH[o] = h;
    qTL[o] = f2bf(v - bf2f(h));
  }
}

// colsum over qT rows, split 4-way over K (blockIdx.z); atomicAdd into zeroed S.
__global__ void k_colsum_qT(float* __restrict__ S, const unsigned short* __restrict__ qTH,
                            const unsigned short* __restrict__ qTL, int gbase){
  int j = blockIdx.x*256 + threadIdx.x;
  int bl = blockIdx.y;
  int kq = blockIdx.z;           // 0..3, each covers LQP/4 columns
  if (j >= HKc) return;
  const ushort4* ph = (const ushort4*)(qTH + ((size_t)bl*HKc + j)*LQP) + kq*(LQP/16);
  const ushort4* pl = (const ushort4*)(qTL + ((size_t)bl*HKc + j)*LQP) + kq*(LQP/16);
  float s=0.f;
  for (int t=0;t<LQP/16;t++){
    ushort4 a = ph[t], c = pl[t];
    s += bf2f(a.x)+bf2f(a.y)+bf2f(a.z)+bf2f(a.w);
    s += bf2f(c.x)+bf2f(c.y)+bf2f(c.z)+bf2f(c.w);
  }
  atomicAdd(&S[(gbase+bl)*HKc + j], s);
}

// Gq = q^T q via split-bf16 MFMA. ZERO LDS / ZERO barriers.
// Split-K by 2 (ks): each half does 28 of 56 chunks, atomicAdd into zeroed Gqp.
// graph = blk & 7 keeps one graph per XCD (L2 pinning).
__global__ void k_gramT(float* __restrict__ Gp, const unsigned short* __restrict__ qTH,
                        const unsigned short* __restrict__ qTL, int gbase){
  int blk = blockIdx.x;
  int bl = blk & 7;
  int ks = (blk >> 3) & 1;
  int tl0 = blk >> 4;
  int bg = gbase + bl;
  int tl = tl0; int ti = 0;
  while (tl >= 12-ti){ tl -= 12-ti; ti++; }
  int tj = ti + tl;
  int r0 = ti*64, c0 = tj*64;
  const unsigned short* qH = qTH + (size_t)bl*HKc*LQP;
  const unsigned short* qL = qTL + (size_t)bl*HKc*LQP;
  float* Gb = Gp + ((size_t)bg*NT + tl0)*TSZ;
  int tid = threadIdx.x;
  int w = tid>>6, l = tid&63, lr = l&31, lg = l>>5;
  int mi = w>>1, ni = w&1;
  const unsigned short* aHp = qH + (size_t)(r0 + mi*32 + lr)*LQP + lg*8;
  const unsigned short* aLp = qL + (size_t)(r0 + mi*32 + lr)*LQP + lg*8;
  const unsigned short* bHp = qH + (size_t)(c0 + ni*32 + lr)*LQP + lg*8;
  const unsigned short* bLp = qL + (size_t)(c0 + ni*32 + lr)*LQP + lg*8;
  f32x16 acc = {};
  int cs = ks*28;
  #pragma unroll 4
  for (int c=cs; c<cs+28; c++){
    bf16x8 aH = *(const bf16x8*)(aHp + c*16);
    bf16x8 aL = *(const bf16x8*)(aLp + c*16);
    bf16x8 bH = *(const bf16x8*)(bHp + c*16);
    bf16x8 bL = *(const bf16x8*)(bLp + c*16);
    acc = __builtin_amdgcn_mfma_f32_32x32x16_bf16(aH, bH, acc, 0,0,0);
    acc = __builtin_amdgcn_mfma_f32_32x32x16_bf16(aH, bL, acc, 0,0,0);
    acc = __builtin_amdgcn_mfma_f32_32x32x16_bf16(aL, bH, acc, 0,0,0);
  }
  #pragma unroll
  for (int reg=0; reg<16; reg++){
    int row = (reg&3) + 8*(reg>>2) + 4*lg;
    atomicAdd(&Gb[(size_t)(mi*32+row)*64 + ni*32 + lr], acc[reg]);
  }
}

// ---------------- v side (fp32, proven R6 path) ----------------
__global__ void k_vgemm8(float* __restrict__ v, const float* __restrict__ vd,
                         const float* __restrict__ W, const float* __restrict__ bias){
  int j = blockIdx.x*256 + threadIdx.x;
  int r0 = blockIdx.y*8;
  __shared__ float xr[8][Dd];
  for (int idx=threadIdx.x; idx<8*Dd; idx+=256){
    int r = idx>>7, k = idx&127;
    xr[r][k] = vd[(size_t)(r0 + r)*Dd + k];
  }
  __syncthreads();
  float acc[8];
  float bj = bias[j];
  #pragma unroll
  for (int r=0;r<8;r++) acc[r]=bj;
  for (int k=0;k<Dd;k++){
    float wk = W[(size_t)k*HKc+j];
    #pragma unroll
    for (int r=0;r<8;r++) acc[r] += xr[r][k]*wk;
  }
  #pragma unroll
  for (int r=0;r<8;r++)
    v[(size_t)(r0+r)*HKc + j] = fmaxf(acc[r],0.f);
}

__global__ void k_colsum_v(float* __restrict__ S, const float* __restrict__ X){
  int j = blockIdx.x*blockDim.x + threadIdx.x;
  int bl = blockIdx.y;
  if (j >= HKc) return;
  const float* p = X + (size_t)bl*NPGc*HKc + j;
  float s=0.f;
  for (int t=0;t<NPGc;t++) s += p[(size_t)t*HKc];
  S[bl*HKc + j] = s;
}

// gramf over packed upper-triangle tiles (fp32 4x4, LDS-tiled).
// 1-D grid blk = tl0*32 + bg -> XCD = bg%8: graphs {g,g+8,g+16,g+24} pin to one
// XCD, so each XCD's L2 holds 4 graphs' V (~3.6 MB) and V is fetched ~once.
__global__ void k_gramf_sym(float* __restrict__ f, const float* __restrict__ V,
                            const float* __restrict__ Gp, const float* __restrict__ hm){
  int blk = blockIdx.x;
  int bg = blk & 31;
  int tl0 = blk >> 5;
  int tl = tl0; int ti = 0;
  while (tl >= 12-ti){ tl -= 12-ti; ti++; }
  int tj = ti + tl;
  int r0 = ti*64, c0 = tj*64;
  int offdiag = (ti != tj);
  const float* Vb = V + (size_t)bg*NPGc*HKc;
  __shared__ float As[16][64], Bs[16][64];
  __shared__ float wc[64], wr[64];
  int tid = threadIdx.x;
  int tx = tid & 15, ty = tid >> 4;
  int ldr = tid >> 4, ldc = (tid & 15)*4;
  if (tid < 64) wc[tid] = hm[c0+tid] + hm[HKc + c0 + tid];
  else if (tid < 128) wr[tid-64] = hm[r0+tid-64] + hm[HKc + r0 + tid-64];
  float acc[4][4] = {};
  for (int t0=0; t0<NPGc; t0+=16){
    float4 av = make_float4(0.f,0.f,0.f,0.f), bv4 = make_float4(0.f,0.f,0.f,0.f);
    if (t0+ldr < NPGc){
      const float* row = Vb + (size_t)(t0+ldr)*HKc;
      av  = *(const float4*)(row + r0 + ldc);
      bv4 = *(const float4*)(row + c0 + ldc);
    }
    *(float4*)&As[ldr][ldc] = av;
    *(float4*)&Bs[ldr][ldc] = bv4;
    __syncthreads();
    #pragma unroll
    for (int tt=0; tt<16; tt++){
      float a[4], bb[4];
      *(float4*)a  = *(const float4*)&As[tt][ty*4];
      *(float4*)bb = *(const float4*)&Bs[tt][tx*4];
      #pragma unroll
      for (int i=0;i<4;i++)
        #pragma unroll
        for (int j=0;j<4;j++) acc[i][j] += a[i]*bb[j];
    }
    __syncthreads();
  }
  const float* gqb = Gp + ((size_t)bg*NT + tl0)*TSZ;
  float w0 = wc[tx*4+0], w1 = wc[tx*4+1], w2 = wc[tx*4+2], w3 = wc[tx*4+3];
  float colp[4] = {0.f,0.f,0.f,0.f};
  #pragma unroll
  for (int i=0;i<4;i++){
    int rl = ty*4 + i;
    int r = r0 + rl;
    const float4 g4 = *(const float4*)(gqb + rl*64 + tx*4);
    float s = acc[i][0]*w0*g4.x + acc[i][1]*w1*g4.y
            + acc[i][2]*w2*g4.z + acc[i][3]*w3*g4.w;
    s += __shfl_xor(s, 1); s += __shfl_xor(s, 2);
    s += __shfl_xor(s, 4); s += __shfl_xor(s, 8);
    if (tx==0) atomicAdd(&f[bg*HKc + r], s);
    if (offdiag){
      float wri = wr[rl];
      colp[0] += acc[i][0]*wri*g4.x;
      colp[1] += acc[i][1]*wri*g4.y;
      colp[2] += acc[i][2]*wri*g4.z;
      colp[3] += acc[i][3]*wri*g4.w;
    }
  }
  if (offdiag){
    #pragma unroll
    for (int j=0;j<4;j++){
      colp[j] += __shfl_xor(colp[j], 16);
      colp[j] += __shfl_xor(colp[j], 32);
    }
    if ((tid & 48) == 0){
      #pragma unroll
      for (int j=0;j<4;j++)
        atomicAdd(&f[bg*HKc + c0 + tx*4 + j], colp[j]);
    }
  }
}

// batched pool over 3 views
__global__ void k_pool3(float* __restrict__ fp, const float* __restrict__ f3,
                        const float* __restrict__ Sv3, const float* __restrict__ Sq,
                        const float* __restrict__ hb){
  int idx = blockIdx.x*256 + threadIdx.x;
  if (idx >= 3*Bc*256) return;
  int v = idx >> 13;
  int rem = idx & 8191;
  int b = rem >> 8, c = rem & 255;
  const float* f = f3 + (size_t)v*Bc*HKc;
  const float* Sv = Sv3 + (size_t)v*Bc*HKc;
  float hbs = hb[0] + hb[1];
  float s = 0.f;
  #pragma unroll
  for (int r=0;r<3;r++){
    int k = c*3 + r;
    s += f[b*HKc + k] + hbs*Sv[b*HKc + k]*Sq[b*HKc + k];
  }
  fp[idx] = s;
}

__global__ void k_bnfeat3(float* __restrict__ y, const float* __restrict__ x, const float* __restrict__ g,
                          const float* __restrict__ bb, int C){
  int c = blockIdx.x; int v = blockIdx.y; int b = threadIdx.x;
  __shared__ float buf[32];
  __shared__ float mv[2];
  int row = v*32 + b;
  float val = x[(size_t)row*C + c];
  buf[b] = val;
  __syncthreads();
  if (b == 0){
    float s = 0.f;
    for (int i=0;i<32;i++) s += buf[i];
    float m = s/32.f;
    float vs = 0.f;
    for (int i=0;i<32;i++){ float d = buf[i]-m; vs += d*d; }
    mv[0] = m; mv[1] = vs/32.f;
  }
  __syncthreads();
  y[(size_t)row*C + c] = (val - mv[0])*rsqrtf(mv[1]+1e-5f)*g[c] + bb[c];
}

__global__ void k_mlp(float* __restrict__ out, const float* __restrict__ in, const float* __restrict__ W,
                      const float* __restrict__ bias, int K, int Nc, int doRelu){
  int b = blockIdx.y;
  int j = blockIdx.x*blockDim.x + threadIdx.x;
  __shared__ float xr[512];
  for (int k=threadIdx.x; k<K; k+=blockDim.x) xr[k] = in[(size_t)b*K+k];
  __syncthreads();
  if (j >= Nc) return;
  float s = bias[j];
  for (int k=0;k<K;k++) s += xr[k]*W[(size_t)k*Nc + j];
  if (doRelu) s = fmaxf(s, 0.f);
  out[(size_t)b*Nc + j] = s;
}

__global__ void k_score96(float* __restrict__ sc, const float* __restrict__ h, const float* __restrict__ w,
                          const float* __restrict__ bb){
  int b = threadIdx.x; if (b>=96) return;
  float s = bb[0];
  for (int k=0;k<Dd;k++) s += h[(size_t)b*Dd+k]*w[k];
  sc[b] = s;
}

__global__ void k_out(float* __restrict__ out, const float* __restrict__ scores){
  int t = threadIdx.x;
  __shared__ float loss_s;
  if (t == 0){
    float sn1[32], sn2[32];
    for (int i=0;i<32;i++){
      float a = scores[32+i]; sn1[i] = a / fmaxf(fabsf(a), 1e-12f);
      float c = scores[64+i]; sn2[i] = c / fmaxf(fabsf(c), 1e-12f);
    }
    float acc = 0.f;
    for (int i=0;i<32;i++){
      float mx = -1e30f;
      for (int j=0;j<32;j++) mx = fmaxf(mx, sn1[i]*sn2[j]);
      float se = 0.f;
      for (int j=0;j<32;j++) se += expf(sn1[i]*sn2[j]-mx);
      acc += sn1[i]*sn2[i] - (mx + logf(se));
    }
    loss_s = -acc/32.f;
  }
  __syncthreads();
  out[t*4+0] = scores[t];
  out[t*4+1] = scores[32+t];
  out[t*4+2] = scores[64+t];
  out[t*4+3] = loss_s;
}

extern "C" void kernel_launch(void* const* d_in, const int* in_sizes, int n_in,
                              void* d_out, int out_size, void* d_ws, size_t ws_size,
                              hipStream_t stream){
  static const int exp_sizes[38] = {
    Nn*INFc, Ec, Ec, Bc*LPc, INFc*Dd,
    9*Dd*Dd, 9*Dd, 9*Dd*Dd, 9*Dd,
    26*Dd, Dd*Dd*3, Dd*Dd*6, Dd*Dd*9, 3*Dd, 3*Dd, 3*Dd,
    Dd*HKc, HKc, Dd*HKc, HKc, 2*HKc, 2, 256, 256,
    256*512, 512, 512*512, 512, 512*128, 128, 128, 1,
    512, 512, 512, 512, 128, 128 };
  if (n_in != 38){ k_sentinel<<<1,128,0,stream>>>((float*)d_out, 2000.f + n_in); return; }
  for (int i=0;i<38;i++){
    if (in_sizes[i] != exp_sizes[i]){
      k_sentinel<<<1,128,0,stream>>>((float*)d_out, 1000.f + i); return;
    }
  }

  const float* node_h=(const float*)d_in[0];
  const int*  esrc  =(const int*)d_in[1];
  const int*  edst  =(const int*)d_in[2];
  const int*  vp    =(const int*)d_in[3];
  const float* W_init=(const float*)d_in[4];
  const float* gcn_W =(const float*)d_in[5];
  const float* gcn_b =(const float*)d_in[6];
  const float* gcn_Wr=(const float*)d_in[7];
  const float* gcn_br=(const float*)d_in[8];
  const float* emb   =(const float*)d_in[9];
  const float* c1w=(const float*)d_in[10];
  const float* c2w=(const float*)d_in[11];
  const float* c3w=(const float*)d_in[12];
  const float* cbv=(const float*)d_in[13];
  const float* bng=(const float*)d_in[14];
  const float* bnb=(const float*)d_in[15];
  const float* Wv =(const float*)d_in[16];
  const float* bvv=(const float*)d_in[17];
  const float* Wq =(const float*)d_in[18];
  const float* bq =(const float*)d_in[19];
  const float* hmat =(const float*)d_in[20];
  const float* hbias=(const float*)d_in[21];
  const float* bang =(const float*)d_in[22];
  const float* banb =(const float*)d_in[23];
  const float* mw1=(const float*)d_in[24]; const float* mb1=(const float*)d_in[25];
  const float* mw2=(const float*)d_in[26]; const float* mb2=(const float*)d_in[27];
  const float* mw3=(const float*)d_in[28]; const float* mb3=(const float*)d_in[29];
  const float* mw4=(const float*)d_in[30]; const float* mb4=(const float*)d_in[31];
  const float* g1=(const float*)d_in[32]; const float* bb1=(const float*)d_in[33];
  const float* g2=(const float*)d_in[34]; const float* bb2=(const float*)d_in[35];
  const float* g3=(const float*)d_in[36]; const float* bb3=(const float*)d_in[37];

  float* ws = (float*)d_ws;
  size_t off = 0;
  auto alloc = [&](size_t n){ float* p = ws + off; off += n; return p; };

  const size_t NDsz = (size_t)Nn*Dd;              // 1,187,840
  const size_t CNNBP = (size_t)Bc*Dd*S1;          // 3,702,784
  const size_t ADJ  = (size_t)Bc*NPGc*NPGc;       // 2,691,200
  const size_t QTF  = (size_t)8*HKc*LQP;          // qT hi+lo as float-slots: 5,505,024
  const size_t VB   = (size_t)Bc*NPGc*HKc;        // 7,127,040
  const size_t AGGF = (size_t)3*Nn*Dd;            // agg hi+lo as float-slots: 3,563,520
  size_t ARENA = 7*NDsz + ADJ + AGGF;             // 14,569,600
  if (ARENA < 4*NDsz + VB) ARENA = 4*NDsz + VB;   // 11,878,400
  if (ARENA < CNNBP + QTF) ARENA = CNNBP + QTF;
  if (ARENA < 2*CNNBP) ARENA = 2*CNNBP;

  // smalls
  float* Sq   = alloc((size_t)Bc*HKc);
  float* Sv3  = alloc((size_t)3*Bc*HKc);
  float* fbuf3= alloc((size_t)3*Bc*HKc);
  float* fpool3=alloc((size_t)3*Bc*256);
  float* hh1  = alloc((size_t)96*512);
  float* hh2  = alloc((size_t)96*512);
  float* hh3  = alloc((size_t)96*128);
  float* sc   = alloc(96);
  float* scl1 = alloc(128); float* shf1 = alloc(128);
  float* scl2 = alloc(128); float* shf2 = alloc(128);
  float* scl3 = alloc(128); float* shf3 = alloc(128);
  float* b1f  = alloc(128); float* b2f  = alloc(128); float* b3f = alloc(128);
  // fragment-packed conv weights (hi+lo): KT*128 float-slots each
  unsigned short* wp1 = (unsigned short*)alloc((size_t)384*128);
  unsigned short* wp2 = (unsigned short*)alloc((size_t)768*128);
  unsigned short* wp3 = (unsigned short*)alloc((size_t)1152*128);
  // GCN weights fragment-packed (hi+lo)
  unsigned short* WTs  = (unsigned short*)alloc(147456);
  unsigned short* WrTs = (unsigned short*)alloc(147456);
  // Wq fragment-packed (hi+lo): 2*8*768*16 ushorts = 98,304 float-slots
  unsigned short* WqTs = (unsigned short*)alloc(98304);
  float* Gqp = alloc((size_t)Bc*NT*TSZ);          // packed triangle: 10,223,616
  float* arena = alloc(ARENA);

  // phase views
  float* cnnA = arena;                  // CNN out (S3-padded) lives here
  float* cnnB = arena + CNNBP;
  float* qbuf = arena + CNNBP;          // qT as bf16 hi/lo (QTF float-slots)
  unsigned short* qTH = (unsigned short*)qbuf;
  unsigned short* qTL = qTH + (size_t)8*HKc*LQP;
  float* h0b  = arena;                  // [0, NDsz)
  float* Bb   = arena + NDsz;           // 3 bufs [NDsz, 4*NDsz)
  float* Cb   = arena + 4*NDsz;         // 3 bufs [4N, 7N)
  float* Adj  = arena + 7*NDsz;         // [7N, 7N+ADJ)
  unsigned short* aggH = (unsigned short*)(arena + 7*NDsz + ADJ);
  unsigned short* aggL = aggH + (size_t)3*Nn*Dd;
  float* vbuf = arena + 4*NDsz;         // BAN phase: fp32 V [4N, 4N+VB)

  // ---- prepacks (layer-1 conv weights need no BN fold) ----
  k_wpack16<<<(24*2048+255)/256,256,0,stream>>>(wp1, c1w, nullptr, 3, 24);
  k_bfold<<<128,128,0,stream>>>(b1f, c1w, nullptr, cbv, 0, 3);
  k_wsplit<<<(9*Dd*Dd+255)/256,256,0,stream>>>(WTs, WrTs, gcn_W, gcn_Wr);
  k_wsplitV<<<(Dd*HKc+255)/256,256,0,stream>>>(WqTs, Wq);

  // ---- ProteinCNN (BN folded into weights/bias of the NEXT conv) ----
  k_embed<<<dim3((LPc+127)/128, Dd, Bc),128,0,stream>>>(cnnB, vp, emb);
  k_convmfma2<3><<<dim3(15,Bc),256,0,stream>>>(cnnA, cnnB, wp1, b1f, 898, 900, S1);
  k_bnc_stats2<<<Dd,256,0,stream>>>(scl1, shf1, cnnA, 898, S1, bng, bnb, 0);
  k_wpack16<<<(48*2048+255)/256,256,0,stream>>>(wp2, c2w, scl1, 6, 48);
  k_bfold<<<128,128,0,stream>>>(b2f, c2w, shf1, cbv, 128, 6);
  k_convmfma2<6><<<dim3(14,Bc),256,0,stream>>>(cnnB, cnnA, wp2, b2f, 893, S1, S2);
  k_bnc_stats2<<<Dd,256,0,stream>>>(scl2, shf2, cnnB, 893, S2, bng, bnb, 128);
  k_wpack16<<<(72*2048+255)/256,256,0,stream>>>(wp3, c3w, scl2, 9, 72);
  k_bfold<<<128,128,0,stream>>>(b3f, c3w, shf2, cbv, 256, 9);
  k_convmfma2<9><<<dim3(14,Bc),256,0,stream>>>(cnnA, cnnB, wp3, b3f, 885, S2, S3);
  k_bnc_stats2<<<Dd,256,0,stream>>>(scl3, shf3, cnnA, 885, S3, bng, bnb, 256);

  // ---- q branch: 4 passes of 8 graphs; MFMA qT; split-K MFMA gram ----
  hipMemsetAsync(Sq, 0, (size_t)Bc*HKc*sizeof(float), stream);
  for (int gb = 0; gb < Bc; gb += 8){
    k_qgemmT<<<dim3(HKc/64,LQP/64,8),256,0,stream>>>(qTH, qTL, cnnA, WqTs, bq, scl3, shf3, gb);
    k_colsum_qT<<<dim3(3,8,4),256,0,stream>>>(Sq, qTH, qTL, gb);
    hipMemsetAsync(Gqp + (size_t)gb*NT*TSZ, 0, (size_t)8*NT*TSZ*sizeof(float), stream);
    k_gramT<<<NT*16,256,0,stream>>>(Gqp, qTH, qTL, gb);
  }

  // ---- dense adjacency ----
  hipMemsetAsync(Adj, 0, ADJ*sizeof(float), stream);
  k_build_adj<<<(Ec+255)/256,256,0,stream>>>(Adj, esrc, edst);

  hipMemsetAsync(fbuf3, 0, (size_t)3*Bc*HKc*sizeof(float), stream);

  // ---- GCN: h0 once, then per layer: MFMA agg + MFMA fused linear ----
  k_h0<<<Nn,Dd,0,stream>>>(h0b, node_h, W_init);
  k_aggm<<<dim3(5,Bc,3),256,0,stream>>>(aggH, aggL, h0b, 0, Adj);
  k_gcnlin<<<dim3(145,3),256,0,stream>>>(Bb, NDsz, aggH, aggL, h0b, 0, WTs, WrTs, gcn_b, gcn_br, 0);
  k_aggm<<<dim3(5,Bc,3),256,0,stream>>>(aggH, aggL, Bb, NDsz, Adj);
  k_gcnlin<<<dim3(145,3),256,0,stream>>>(Cb, NDsz, aggH, aggL, Bb, NDsz, WTs, WrTs, gcn_b, gcn_br, 1);
  k_aggm<<<dim3(5,Bc,3),256,0,stream>>>(aggH, aggL, Cb, NDsz, Adj);
  k_gcnlin<<<dim3(145,3),256,0,stream>>>(Bb, NDsz, aggH, aggL, Cb, NDsz, WTs, WrTs, gcn_b, gcn_br, 2);

  // ---- BAN per view (fp32 v path; gramf with graph->XCD pinning) ----
  for (int g=0; g<3; g++){
    k_vgemm8<<<dim3(3,(Bc*NPGc)/8),256,0,stream>>>(vbuf, Bb + (size_t)g*NDsz, Wv, bvv);
    k_colsum_v<<<dim3(3,Bc),256,0,stream>>>(Sv3 + (size_t)g*Bc*HKc, vbuf);
    k_gramf_sym<<<NT*32,256,0,stream>>>(fbuf3 + (size_t)g*Bc*HKc, vbuf, Gqp, hmat);
  }

  // ---- batched tail over 3 views (96 rows) ----
  k_pool3<<<(3*Bc*256+255)/256,256,0,stream>>>(fpool3, fbuf3, Sv3, Sq, hbias);
  k_bnfeat3<<<dim3(256,3),32,0,stream>>>(fpool3, fpool3, bang, banb, 256);
  k_mlp<<<dim3(2,96),256,0,stream>>>(hh1, fpool3, mw1, mb1, 256, 512, 1);
  k_bnfeat3<<<dim3(512,3),32,0,stream>>>(hh1, hh1, g1, bb1, 512);
  k_mlp<<<dim3(2,96),256,0,stream>>>(hh2, hh1, mw2, mb2, 512, 512, 1);
  k_bnfeat3<<<dim3(512,3),32,0,stream>>>(hh2, hh2, g2, bb2, 512);
  k_mlp<<<dim3(1,96),256,0,stream>>>(hh3, hh2, mw3, mb3, 512, 128, 1);
  k_bnfeat3<<<dim3(128,3),32,0,stream>>>(hh3, hh3, g3, bb3, 128);
  k_score96<<<1,96,0,stream>>>(sc, hh3, mw4, mb4);
  k_out<<<1,32,0,stream>>>((float*)d_out, sc);
}